// Round 12
// baseline (181.822 us; speedup 1.0000x reference)
//
#include <hip/hip_runtime.h>

typedef __attribute__((ext_vector_type(8)))  short bf16x8;   // 8 bf16 in 4 VGPRs
typedef __attribute__((ext_vector_type(4)))  float f32x4;
typedef __attribute__((ext_vector_type(16))) float f32x16;
typedef __attribute__((ext_vector_type(8)))  unsigned short u16x8;

#define HW 4096
#define CDIM 256

#if __has_builtin(__builtin_amdgcn_exp2f)
#define EXP2(x) __builtin_amdgcn_exp2f(x)
#else
#define EXP2(x) exp2f(x)
#endif

__device__ __forceinline__ unsigned short f2bf(float f) {   // RTNE
    union { float f; unsigned u; } v; v.f = f;
    unsigned r = v.u + 0x7fffu + ((v.u >> 16) & 1u);
    return (unsigned short)(r >> 16);
}
__device__ __forceinline__ float bf2f(unsigned short u) {
    union { unsigned u; float f; } v; v.u = ((unsigned)u) << 16;
    return v.f;
}
// pack bf16(hi)|bf16(lo) — truncation via v_perm_b32
__device__ __forceinline__ unsigned pk2(float hi, float lo) {
    union { float f; unsigned u; } a, b; a.f = hi; b.f = lo;
    return __builtin_amdgcn_perm(a.u, b.u, 0x07060302u);
}
// async global->LDS, 16B per lane; LDS dest = wave-uniform base + lane*16
__device__ __forceinline__ void gl_lds16(const void* g, void* l) {
    __builtin_amdgcn_global_load_lds(
        (const __attribute__((address_space(1))) unsigned int*)(unsigned long long)g,
        (__attribute__((address_space(3))) unsigned int*)(unsigned int)(unsigned long long)l,
        16, 0, 0);
}

// ---------------------------------------------------------------------------
// Kernel 0: pack W (fp32) -> Wpk bf16 [inp][448 o][256 c] row-major. (frozen)
// ---------------------------------------------------------------------------
__global__ __launch_bounds__(256) void wpack_kernel(
    const float* __restrict__ Wq1, const float* __restrict__ Wk1,
    const float* __restrict__ Wv1, const float* __restrict__ Wq2,
    const float* __restrict__ Wk2, const float* __restrict__ Wv2,
    unsigned short* __restrict__ Wpk)
{
    const int i  = blockIdx.x * 256 + threadIdx.x;     // 0..57343
    const int c4 = i & 63;
    const int r6 = i >> 6;                             // 0..895
    const int inp = r6 / 448;
    const int o   = r6 - inp * 448;
    const float* src;
    int orow;
    if (o < 64)       { src = inp ? Wq2 : Wq1; orow = o; }
    else if (o < 192) { src = inp ? Wk2 : Wk1; orow = o - 64; }
    else              { src = inp ? Wv2 : Wv1; orow = o - 192; }
    const float4 v = *(const float4*)(src + (size_t)orow * CDIM + c4 * 4);
    uint2 pkd; pkd.x = pk2(v.y, v.x); pkd.y = pk2(v.w, v.z);
    ((uint2*)Wpk)[i] = pkd;
}

// ---------------------------------------------------------------------------
// Kernel 1: projections. CHANGED this round (epilogue store coalescing):
//   old epilogue: 56 scalar 2-B global stores/thread (K/V in 32-B segments,
//   Q stride-2 scatter). K's per-block dest is CONTIGUOUS 8 KB in global;
//   V rows allow 64-B segments. New: K/V results staged in LDS tiles
//   (kt[32][136], vt[256][40]; padded strides, 16-B-aligned copy-out;
//   union with dead xb buffer, 28.5 KB), then cooperative u16x8 copy-out:
//   K = contiguous 8 KB block write, V = 16-B stores / 64-B segments.
//   Scalar stores 56 -> 16/thread (Q keeps interleaved layout — forced by
//   attn fragment layout). Math bit-identical. +2 barriers.
// ---------------------------------------------------------------------------
__global__ __launch_bounds__(256) void proj_kernel(
    const float* __restrict__ in1, const float* __restrict__ in2,
    const float* __restrict__ bq1, const float* __restrict__ bk1,
    const float* __restrict__ bv1, const float* __restrict__ bq2,
    const float* __restrict__ bk2, const float* __restrict__ bv2,
    const unsigned short* __restrict__ Wpk,
    unsigned short* __restrict__ Qg, unsigned short* __restrict__ Kg,
    unsigned short* __restrict__ Vg)
{
    // union: phase 1 xb[32*128] u32 (16 KB); phase 2 kt 32x136 + vt 256x40 bf16
    __shared__ __align__(16) char smem[29184];
    unsigned*       xb = (unsigned*)smem;
    unsigned short* kt = (unsigned short*)smem;              // [n 32][136]
    unsigned short* vt = (unsigned short*)(smem + 8704);     // [c 256][40]

    const int bid   = blockIdx.x;
    const int ntile = bid & 127;
    const int inp   = (bid >> 7) & 1;
    const int b     = bid >> 8;

    const float* X  = (inp ? in2 : in1) + (size_t)b * CDIM * HW;
    const float* bq = inp ? bq2 : bq1;
    const float* bk = inp ? bk2 : bk1;
    const float* bv = inp ? bv2 : bv1;
    const unsigned short* Wb = Wpk + (size_t)inp * 448 * CDIM;

    const int tid  = threadIdx.x;
    const int lane = tid & 63;
    const int w    = tid >> 6;
    const int l15  = lane & 15, quad = lane >> 4;
    const int n0   = ntile * 32;

    // ---- stage X -> LDS (bf16 pairs, transposed to [n][ci]) ----
#pragma unroll
    for (int t = 0; t < 4; ++t) {
        const int idx = t * 256 + tid;       // 0..1023
        const int cp  = idx >> 3;            // ci-pair 0..127
        const int n4  = idx & 7;             // float4 index along n
        const float* p0 = X + (size_t)(cp * 2) * HW + n0 + n4 * 4;
        const float4 a = *(const float4*)p0;
        const float4 bb = *(const float4*)(p0 + HW);
        const float av[4] = {a.x, a.y, a.z, a.w};
        const float bv4[4] = {bb.x, bb.y, bb.z, bb.w};
#pragma unroll
        for (int r = 0; r < 4; ++r) {
            const int n = n4 * 4 + r;
            xb[n * 128 + (((cp >> 2) ^ (n & 7)) << 2) + (cp & 3)] = pk2(bv4[r], av[r]);
        }
    }
    __syncthreads();

    f32x4 acc[7][2];
#pragma unroll
    for (int i = 0; i < 7; ++i)
#pragma unroll
        for (int j = 0; j < 2; ++j) acc[i][j] = (f32x4){0.f, 0.f, 0.f, 0.f};

#pragma unroll
    for (int kk = 0; kk < 8; ++kk) {
        bf16x8 xf[2];
#pragma unroll
        for (int ns = 0; ns < 2; ++ns) {
            const int nrow = ns * 16 + l15;
            xf[ns] = *(const bf16x8*)&xb[nrow * 128 + (((kk * 4 + quad) ^ (nrow & 7)) << 2)];
        }
#pragma unroll
        for (int os = 0; os < 7; ++os) {
            const int ob = w * 7 + os;
            const int og = ob * 16 + l15;
            const bf16x8 wf = *(const bf16x8*)(Wb + (size_t)og * CDIM + kk * 32 + quad * 8);
            if (ob < 12) {   // Q,K: Out^T -> A = X-frag, B = W-frag
#pragma unroll
                for (int ns = 0; ns < 2; ++ns)
                    acc[os][ns] = __builtin_amdgcn_mfma_f32_16x16x32_bf16(xf[ns], wf, acc[os][ns], 0, 0, 0);
            } else {         // V: Out -> A = W-frag, B = X-frag
#pragma unroll
                for (int ns = 0; ns < 2; ++ns)
                    acc[os][ns] = __builtin_amdgcn_mfma_f32_16x16x32_bf16(wf, xf[ns], acc[os][ns], 0, 0, 0);
            }
        }
    }

    const size_t qbase = (size_t)b * HW * 128;
    const size_t kbase = (size_t)(b * 2 + inp) * HW * 128;
    const size_t vbase = (size_t)(b * 2 + inp) * (size_t)CDIM * HW;

    __syncthreads();    // all xb reads done; smem reused as kt/vt

#pragma unroll
    for (int os = 0; os < 7; ++os) {
        const int ob = w * 7 + os;
        if (ob < 4) {
            // Q: scalar stores (interleaved global layout), unchanged
            const int o = ob * 16 + l15;
            const float bb = bq[o];
#pragma unroll
            for (int ns = 0; ns < 2; ++ns) {
                const f32x4 d = acc[os][ns];
#pragma unroll
                for (int r = 0; r < 4; ++r) {
                    const int n = n0 + ns * 16 + quad * 4 + r;
                    // pre-scale Q by log2(e): attn computes exp2(S) == exp(S)
                    Qg[qbase + (size_t)n * 128 + 2 * o + inp] =
                        f2bf((d[r] + bb) * 1.4426950408889634f);
                }
            }
        } else if (ob < 12) {
            const int c = (ob - 4) * 16 + l15;
            const float bb = bk[c];
#pragma unroll
            for (int ns = 0; ns < 2; ++ns) {
                const f32x4 d = acc[os][ns];
#pragma unroll
                for (int r = 0; r < 4; ++r) {
                    const int nl = ns * 16 + quad * 4 + r;
                    kt[nl * 136 + c] = f2bf(d[r] + bb);
                }
            }
        } else {
            const int c0 = (ob - 12) * 16 + quad * 4;
#pragma unroll
            for (int ns = 0; ns < 2; ++ns) {
                const f32x4 d = acc[os][ns];
#pragma unroll
                for (int r = 0; r < 4; ++r) {
                    const int nl = ns * 16 + l15;
                    vt[(c0 + r) * 40 + nl] = f2bf(d[r] + bv[c0 + r]);
                }
            }
        }
    }
    __syncthreads();

    // K copy-out: dest region [n0..n0+32) x 128 is CONTIGUOUS 8 KB in Kg
    {
        unsigned short* kb2 = Kg + kbase + (size_t)n0 * 128;
#pragma unroll
        for (int p = 0; p < 2; ++p) {
            const int idx = p * 2048 + tid * 8;
            const int n = idx >> 7, c = idx & 127;
            *(u16x8*)(kb2 + idx) = *(const u16x8*)(kt + n * 136 + c);
        }
    }
    // V copy-out: 16-B stores, 64-B contiguous segments per c-row
    {
#pragma unroll
        for (int p = 0; p < 4; ++p) {
            const int idx = p * 2048 + tid * 8;
            const int c = idx >> 5, nn = idx & 31;
            *(u16x8*)(Vg + vbase + (size_t)c * HW + n0 + nn) =
                *(const u16x8*)(vt + c * 40 + nn);
        }
    }
}

// ---------------------------------------------------------------------------
// Kernel 2: streaming attention — r4-EXACT revert (best measured: 60.5 us,
//   VGPR 124, FETCH 14.4 MB). The ~60.5 us wall is robust to pipelining
//   (r4), 2x occupancy (r9), and counted-vmcnt (r11); accepted as this
//   structure's floor. PV lagged one tile; V triple-buffered; K double.
// ---------------------------------------------------------------------------
__global__ __launch_bounds__(256, 2) void attn_kernel(
    const unsigned short* __restrict__ Qg, const unsigned short* __restrict__ Kg,
    const unsigned short* __restrict__ Vg,
    unsigned short* __restrict__ Op, float* __restrict__ Lp)
{
    __shared__ unsigned short kbuf[2][32 * 16 * 8];   // 16 KB, [m32][128k] swizzled
    __shared__ unsigned short vbuf[3][256 * 4 * 8];   // 48 KB, [c256][32m] swizzled

    const int bid = blockIdx.x;
    const int mq  = bid & 3;                 // m-quarter
    const int set = (bid >> 2) & 3;
    const int att = set & 1, b = set >> 1;
    const int nt  = bid >> 4;                // 0..31
    const int n0g = nt * 128;
    const int mbase = mq * 1024;
    const int tid = threadIdx.x;
    const int lane = tid & 63, w = tid >> 6;
    const int l31 = lane & 31, h = lane >> 5;

    const unsigned short* Qb = Qg + (size_t)b * HW * 128;
    const unsigned short* Kb = Kg + (size_t)(b * 2 + att) * HW * 128;
    const unsigned short* Vb = Vg + (size_t)(b * 2 + att) * (size_t)CDIM * HW;

    bf16x8 aQ[8];   // QK B-operand fragment; wave owns n-range n0g + w*32
    {
        const int n = n0g + w * 32 + l31;
#pragma unroll
        for (int kk = 0; kk < 8; ++kk)
            aQ[kk] = *(const bf16x8*)(Qb + (size_t)n * 128 + kk * 16 + h * 8);
    }

    f32x16 acc[8];
#pragma unroll
    for (int i = 0; i < 8; ++i)
#pragma unroll
        for (int r = 0; r < 16; ++r) acc[i][r] = 0.f;
    float lsum = 0.f;

    // per-lane global src pointers (verified r2/r4 scheme)
    const unsigned short* ksrc[2];
    const unsigned short* vsrc[4];
#pragma unroll
    for (int t = 0; t < 2; ++t) {
        const int L = (t * 4 + w) * 64 + lane;
        const int ml = L >> 4, s = L & 15;
        ksrc[t] = Kb + (size_t)ml * 128 + (s ^ (ml & 15)) * 8;
    }
#pragma unroll
    for (int t = 0; t < 4; ++t) {
        const int L = (t * 4 + w) * 64 + lane;
        const int c = L >> 2, s = L & 3;
        vsrc[t] = Vb + (size_t)c * HW + (s ^ ((c >> 2) & 3)) * 8;
    }

    auto stage = [&](int mt) {
        const int kb = mt & 1;
        const int vb = mt % 3;
        const int m0 = mbase + mt * 32;
        char* kdl = (char*)&kbuf[kb][0] + (size_t)w * 1024;       // wave-uniform
        char* vdl = (char*)&vbuf[vb][0] + (size_t)w * 1024;
#pragma unroll
        for (int t = 0; t < 2; ++t)
            gl_lds16(ksrc[t] + (size_t)m0 * 128, kdl + (size_t)t * 4096);
#pragma unroll
        for (int t = 0; t < 4; ++t)
            gl_lds16(vsrc[t] + m0, vdl + (size_t)t * 4096);
    };

    auto QK = [&](const unsigned short* kb_, f32x16& sa, f32x16& sb) {
#pragma unroll
        for (int r = 0; r < 16; ++r) { sa[r] = 0.f; sb[r] = 0.f; }
#pragma unroll
        for (int kk = 0; kk < 4; ++kk) {
            bf16x8 bK = *(const bf16x8*)&kb_[(l31 * 16 + ((kk * 2 + h) ^ (l31 & 15))) * 8];
            sa = __builtin_amdgcn_mfma_f32_32x32x16_bf16(bK, aQ[kk], sa, 0, 0, 0);
        }
#pragma unroll
        for (int kk = 4; kk < 8; ++kk) {
            bf16x8 bK = *(const bf16x8*)&kb_[(l31 * 16 + ((kk * 2 + h) ^ (l31 & 15))) * 8];
            sb = __builtin_amdgcn_mfma_f32_32x32x16_bf16(bK, aQ[kk], sb, 0, 0, 0);
        }
    };

    auto EXPP = [&](const f32x16& sa, const f32x16& sb, bf16x8* bP) {
        float p[16];
#pragma unroll
        for (int r = 0; r < 16; ++r) {
            p[r] = EXP2(sa[r] + sb[r]);     // Q pre-scaled by log2e
            lsum += p[r];
        }
#pragma unroll
        for (int k2 = 0; k2 < 2; ++k2) {
            const float* pp = p + k2 * 8;
            const unsigned a0 = pk2(pp[1], pp[0]);
            const unsigned a1 = pk2(pp[3], pp[2]);
            const unsigned b0 = pk2(pp[5], pp[4]);
            const unsigned b1 = pk2(pp[7], pp[6]);
            auto s0 = __builtin_amdgcn_permlane32_swap(a0, b0, false, false);
            auto s1 = __builtin_amdgcn_permlane32_swap(a1, b1, false, false);
            union { unsigned u[4]; bf16x8 v; } uu;
            uu.u[0] = s0[0];
            uu.u[1] = s1[0];
            uu.u[2] = s0[1];
            uu.u[3] = s1[1];
            bP[k2] = uu.v;
        }
    };

    auto PV = [&](const unsigned short* vb_, const bf16x8* bP) {
#pragma unroll
        for (int cf = 0; cf < 8; ++cf) {
            const int c = cf * 32 + l31;
#pragma unroll
            for (int k2 = 0; k2 < 2; ++k2) {
                bf16x8 aV = *(const bf16x8*)&vb_[(c * 4 + ((k2 * 2 + h) ^ ((c >> 2) & 3))) * 8];
                acc[cf] = __builtin_amdgcn_mfma_f32_32x32x16_bf16(aV, bP[k2], acc[cf], 0, 0, 0);
            }
        }
    };

    // ---- pipelined main loop: iter mt does QK(mt) + PV(mt-1) ----
    stage(0);
    __syncthreads();                        // K0,V0 ready
    stage(1);
    bf16x8 bP[2];
    {
        f32x16 sa, sb;
        QK(&kbuf[0][0], sa, sb);
        EXPP(sa, sb, bP);
    }
    int vprev = 0;                          // (mt-1)%3 for mt=1
#pragma unroll 1
    for (int mt = 1; mt < 32; ++mt) {
        __syncthreads();                    // drains stage(mt); prev PV reads done
        if (mt + 1 < 32) stage(mt + 1);
        f32x16 sa, sb;
        QK(&kbuf[mt & 1][0], sa, sb);       // QK(mt): independent of...
        PV(&vbuf[vprev][0], bP);            // ...PV(mt-1): MFMA pipe stays fed
        EXPP(sa, sb, bP);                   // overwrites bP for next iter
        vprev = (vprev == 2) ? 0 : vprev + 1;
    }
    PV(&vbuf[vprev][0], bP);                // tail: PV(31)

    // softmax denominator: lane owns n; two h-halves hold disjoint m's
    const float ltot = lsum + __shfl_xor(lsum, 32, 64);
    const int nn = n0g + w * 32 + l31;
    if (h == 0) Lp[(size_t)(mq * 4 + set) * HW + nn] = ltot;

    const size_t obase = (size_t)(mq * 4 + set) * CDIM * HW;
#pragma unroll
    for (int cf = 0; cf < 8; ++cf) {
#pragma unroll
        for (int r = 0; r < 16; ++r) {
            const int c = cf * 32 + (r & 3) + 8 * (r >> 2) + 4 * h;
            Op[obase + (size_t)c * HW + nn] = f2bf(acc[cf][r]);
        }
    }
}

// ---------------------------------------------------------------------------
// Kernel 3: combine partials: out = g*(O0+O1+O2+O3)/(l0+l1+l2+l3) + input.
// (frozen, 4 m-quarter partials)
// ---------------------------------------------------------------------------
__global__ __launch_bounds__(256) void combine_kernel(
    const unsigned short* __restrict__ Op, const float* __restrict__ Lp,
    const float* __restrict__ in1, const float* __restrict__ in2,
    const float* __restrict__ gamma_p, float* __restrict__ out)
{
    const size_t i8 = ((size_t)blockIdx.x * 256 + threadIdx.x) * 8;
    const int oset = (int)(i8 >> 20);          // att*2 + b
    const int att = oset >> 1, b = oset & 1;
    const int pset = b * 2 + att;
    const size_t rem = i8 & 1048575u;          // c*HW + n
    const int n = (int)(i8 & 4095);

    u16x8 o[4];
    f32x4 l0[4], l1[4];
#pragma unroll
    for (int mq = 0; mq < 4; ++mq) {
        o[mq]  = *(const u16x8*)(Op + ((size_t)(mq * 4 + pset) << 20) + rem);
        l0[mq] = *(const f32x4*)(Lp + (size_t)(mq * 4 + pset) * HW + n);
        l1[mq] = *(const f32x4*)(Lp + (size_t)(mq * 4 + pset) * HW + n + 4);
    }
    const float* inb = (att ? in2 : in1) + (size_t)b * CDIM * HW + rem;
    const float g = *gamma_p;

    const f32x4 iv0 = *(const f32x4*)(inb);
    const f32x4 iv1 = *(const f32x4*)(inb + 4);
    f32x4 r0, r1;
#pragma unroll
    for (int j = 0; j < 4; ++j) {
        float ov = 0.f, ld = 0.f;
#pragma unroll
        for (int mq = 0; mq < 4; ++mq) {
            ov += bf2f((unsigned short)o[mq][j]);
            ld += l0[mq][j];
        }
        r0[j] = g * ov / ld + iv0[j];
    }
#pragma unroll
    for (int j = 0; j < 4; ++j) {
        float ov = 0.f, ld = 0.f;
#pragma unroll
        for (int mq = 0; mq < 4; ++mq) {
            ov += bf2f((unsigned short)o[mq][j + 4]);
            ld += l1[mq][j];
        }
        r1[j] = g * ov / ld + iv1[j];
    }
    *(f32x4*)(out + i8) = r0;
    *(f32x4*)(out + i8 + 4) = r1;
}

extern "C" void kernel_launch(void* const* d_in, const int* in_sizes, int n_in,
                              void* d_out, int out_size, void* d_ws, size_t ws_size,
                              hipStream_t stream) {
    const float* in1 = (const float*)d_in[0];
    const float* in2 = (const float*)d_in[1];
    const float* Wq1 = (const float*)d_in[2];  const float* bq1 = (const float*)d_in[3];
    const float* Wk1 = (const float*)d_in[4];  const float* bk1 = (const float*)d_in[5];
    const float* Wv1 = (const float*)d_in[6];  const float* bv1 = (const float*)d_in[7];
    const float* Wq2 = (const float*)d_in[8];  const float* bq2 = (const float*)d_in[9];
    const float* Wk2 = (const float*)d_in[10]; const float* bk2 = (const float*)d_in[11];
    const float* Wv2 = (const float*)d_in[12]; const float* bv2 = (const float*)d_in[13];
    const float* gamma = (const float*)d_in[14];

    unsigned short* Qg = (unsigned short*)d_ws;                 // [2][4096 n][128 c]
    unsigned short* Kg = Qg + (size_t)2 * HW * 128;             // [4][4096 m][128 c]
    unsigned short* Vg = Kg + (size_t)4 * HW * 128;             // [4][256 c][4096 m]
    unsigned short* Op = Vg + (size_t)4 * CDIM * HW;            // [4 mq][4 set][256 c][4096 n] bf16
    float*          Lp = (float*)(Op + (size_t)16 * CDIM * HW); // [4 mq][4 set][4096 n] f32
    unsigned short* Wpk = Op;   // aliases Op: live only wpack->proj, dead before attn

    wpack_kernel<<<224, 256, 0, stream>>>(Wq1, Wk1, Wv1, Wq2, Wk2, Wv2, Wpk);
    proj_kernel<<<512, 256, 0, stream>>>(in1, in2, bq1, bk1, bv1, bq2, bk2, bv2,
                                         Wpk, Qg, Kg, Vg);
    attn_kernel<<<512, 256, 0, stream>>>(Qg, Kg, Vg, Op, Lp);
    combine_kernel<<<2048, 256, 0, stream>>>(Op, Lp, in1, in2, gamma, (float*)d_out);
}

// Round 14
// 177.169 us; speedup vs baseline: 1.0263x; 1.0263x over previous
//
#include <hip/hip_runtime.h>

typedef __attribute__((ext_vector_type(8)))  short bf16x8;   // 8 bf16 in 4 VGPRs
typedef __attribute__((ext_vector_type(4)))  float f32x4;
typedef __attribute__((ext_vector_type(16))) float f32x16;
typedef __attribute__((ext_vector_type(8)))  unsigned short u16x8;

#define HW 4096
#define CDIM 256

#if __has_builtin(__builtin_amdgcn_exp2f)
#define EXP2(x) __builtin_amdgcn_exp2f(x)
#else
#define EXP2(x) exp2f(x)
#endif

__device__ __forceinline__ unsigned short f2bf(float f) {   // RTNE
    union { float f; unsigned u; } v; v.f = f;
    unsigned r = v.u + 0x7fffu + ((v.u >> 16) & 1u);
    return (unsigned short)(r >> 16);
}
__device__ __forceinline__ float bf2f(unsigned short u) {
    union { unsigned u; float f; } v; v.u = ((unsigned)u) << 16;
    return v.f;
}
// pack bf16(hi)|bf16(lo) — truncation via v_perm_b32
__device__ __forceinline__ unsigned pk2(float hi, float lo) {
    union { float f; unsigned u; } a, b; a.f = hi; b.f = lo;
    return __builtin_amdgcn_perm(a.u, b.u, 0x07060302u);
}
// async global->LDS, 16B per lane; LDS dest = wave-uniform base + lane*16
__device__ __forceinline__ void gl_lds16(const void* g, void* l) {
    __builtin_amdgcn_global_load_lds(
        (const __attribute__((address_space(1))) unsigned int*)(unsigned long long)g,
        (__attribute__((address_space(3))) unsigned int*)(unsigned int)(unsigned long long)l,
        16, 0, 0);
}

// ---------------------------------------------------------------------------
// Kernel 0: pack W (fp32) -> Wpk bf16 [inp][448 o][256 c] row-major. (frozen)
// ---------------------------------------------------------------------------
__global__ __launch_bounds__(256) void wpack_kernel(
    const float* __restrict__ Wq1, const float* __restrict__ Wk1,
    const float* __restrict__ Wv1, const float* __restrict__ Wq2,
    const float* __restrict__ Wk2, const float* __restrict__ Wv2,
    unsigned short* __restrict__ Wpk)
{
    const int i  = blockIdx.x * 256 + threadIdx.x;     // 0..57343
    const int c4 = i & 63;
    const int r6 = i >> 6;                             // 0..895
    const int inp = r6 / 448;
    const int o   = r6 - inp * 448;
    const float* src;
    int orow;
    if (o < 64)       { src = inp ? Wq2 : Wq1; orow = o; }
    else if (o < 192) { src = inp ? Wk2 : Wk1; orow = o - 64; }
    else              { src = inp ? Wv2 : Wv1; orow = o - 192; }
    const float4 v = *(const float4*)(src + (size_t)orow * CDIM + c4 * 4);
    uint2 pkd; pkd.x = pk2(v.y, v.x); pkd.y = pk2(v.w, v.z);
    ((uint2*)Wpk)[i] = pkd;
}

// ---------------------------------------------------------------------------
// Kernel 1: projections, v6 (r4-exact, frozen). Q pre-scaled by log2(e).
// ---------------------------------------------------------------------------
__global__ __launch_bounds__(256) void proj_kernel(
    const float* __restrict__ in1, const float* __restrict__ in2,
    const float* __restrict__ bq1, const float* __restrict__ bk1,
    const float* __restrict__ bv1, const float* __restrict__ bq2,
    const float* __restrict__ bk2, const float* __restrict__ bv2,
    const unsigned short* __restrict__ Wpk,
    unsigned short* __restrict__ Qg, unsigned short* __restrict__ Kg,
    unsigned short* __restrict__ Vg)
{
    __shared__ unsigned xb[32 * 128];   // 16 KB: [n][128 ci-pair u32], swizzled

    const int bid   = blockIdx.x;
    const int ntile = bid & 127;
    const int inp   = (bid >> 7) & 1;
    const int b     = bid >> 8;

    const float* X  = (inp ? in2 : in1) + (size_t)b * CDIM * HW;
    const float* bq = inp ? bq2 : bq1;
    const float* bk = inp ? bk2 : bk1;
    const float* bv = inp ? bv2 : bv1;
    const unsigned short* Wb = Wpk + (size_t)inp * 448 * CDIM;

    const int tid  = threadIdx.x;
    const int lane = tid & 63;
    const int w    = tid >> 6;
    const int l15  = lane & 15, quad = lane >> 4;
    const int n0   = ntile * 32;

    // ---- stage X -> LDS (bf16 pairs, transposed to [n][ci]) ----
#pragma unroll
    for (int t = 0; t < 4; ++t) {
        const int idx = t * 256 + tid;       // 0..1023
        const int cp  = idx >> 3;            // ci-pair 0..127
        const int n4  = idx & 7;             // float4 index along n
        const float* p0 = X + (size_t)(cp * 2) * HW + n0 + n4 * 4;
        const float4 a = *(const float4*)p0;
        const float4 bb = *(const float4*)(p0 + HW);
        const float av[4] = {a.x, a.y, a.z, a.w};
        const float bv4[4] = {bb.x, bb.y, bb.z, bb.w};
#pragma unroll
        for (int r = 0; r < 4; ++r) {
            const int n = n4 * 4 + r;
            xb[n * 128 + (((cp >> 2) ^ (n & 7)) << 2) + (cp & 3)] = pk2(bv4[r], av[r]);
        }
    }
    __syncthreads();

    f32x4 acc[7][2];
#pragma unroll
    for (int i = 0; i < 7; ++i)
#pragma unroll
        for (int j = 0; j < 2; ++j) acc[i][j] = (f32x4){0.f, 0.f, 0.f, 0.f};

#pragma unroll
    for (int kk = 0; kk < 8; ++kk) {
        bf16x8 xf[2];
#pragma unroll
        for (int ns = 0; ns < 2; ++ns) {
            const int nrow = ns * 16 + l15;
            xf[ns] = *(const bf16x8*)&xb[nrow * 128 + (((kk * 4 + quad) ^ (nrow & 7)) << 2)];
        }
#pragma unroll
        for (int os = 0; os < 7; ++os) {
            const int ob = w * 7 + os;
            const int og = ob * 16 + l15;
            const bf16x8 wf = *(const bf16x8*)(Wb + (size_t)og * CDIM + kk * 32 + quad * 8);
            if (ob < 12) {   // Q,K: Out^T -> A = X-frag, B = W-frag
#pragma unroll
                for (int ns = 0; ns < 2; ++ns)
                    acc[os][ns] = __builtin_amdgcn_mfma_f32_16x16x32_bf16(xf[ns], wf, acc[os][ns], 0, 0, 0);
            } else {         // V: Out -> A = W-frag, B = X-frag
#pragma unroll
                for (int ns = 0; ns < 2; ++ns)
                    acc[os][ns] = __builtin_amdgcn_mfma_f32_16x16x32_bf16(wf, xf[ns], acc[os][ns], 0, 0, 0);
            }
        }
    }

    const size_t qbase = (size_t)b * HW * 128;
    const size_t kbase = (size_t)(b * 2 + inp) * HW * 128;
    const size_t vbase = (size_t)(b * 2 + inp) * (size_t)CDIM * HW;
#pragma unroll
    for (int os = 0; os < 7; ++os) {
        const int ob = w * 7 + os;
        if (ob < 4) {
            const int o = ob * 16 + l15;
            const float bb = bq[o];
#pragma unroll
            for (int ns = 0; ns < 2; ++ns) {
                const f32x4 d = acc[os][ns];
#pragma unroll
                for (int r = 0; r < 4; ++r) {
                    const int n = n0 + ns * 16 + quad * 4 + r;
                    // pre-scale Q by log2(e): attn computes exp2(S) == exp(S)
                    Qg[qbase + (size_t)n * 128 + 2 * o + inp] =
                        f2bf((d[r] + bb) * 1.4426950408889634f);
                }
            }
        } else if (ob < 12) {
            const int c = (ob - 4) * 16 + l15;
            const float bb = bk[c];
#pragma unroll
            for (int ns = 0; ns < 2; ++ns) {
                const f32x4 d = acc[os][ns];
#pragma unroll
                for (int r = 0; r < 4; ++r) {
                    const int n = n0 + ns * 16 + quad * 4 + r;
                    Kg[kbase + (size_t)n * 128 + c] = f2bf(d[r] + bb);
                }
            }
        } else {
            const int c0 = (ob - 12) * 16 + quad * 4;
#pragma unroll
            for (int ns = 0; ns < 2; ++ns) {
                const f32x4 d = acc[os][ns];
#pragma unroll
                for (int r = 0; r < 4; ++r) {
                    const int n = n0 + ns * 16 + l15;
                    Vg[vbase + (size_t)(c0 + r) * HW + n] = f2bf(d[r] + bv[c0 + r]);
                }
            }
        }
    }
}

// ---------------------------------------------------------------------------
// Kernel 2: streaming attention (in-block m-split, 2 global partials —
//   r13 resubmit with LDS cut 132096 -> 131072 B (128 KiB, the proven
//   per-workgroup max). lred now overlaps dead staging LDS post-loop;
//   its write moved AFTER the first post-loop barrier (final PV reads
//   vbuf[1], which the barrier retires first). All math identical to r13.
//   Structure: 512-thr blocks, 8 waves = nw(4) x mw(2); mw-waves process
//   DISJOINT 32-m subtiles (QK dedup preserved); per-wave body r4-verbatim.
//   Grid 256 = 32 nt x 4 set x 2 mh -> 1 block/CU = 2 waves/SIMD.
//   End: mw=1 waves pass acc via LDS bf16 (same rounding as old Op path);
//   mw=0 sums on-chip, writes Op. Partials 4 -> 2.
//   Gates: FETCH ~15-20 MB, VGPR <= 128, total < 178 else revert to r4.
// ---------------------------------------------------------------------------
__global__ __launch_bounds__(512, 2) void attn_kernel(
    const unsigned short* __restrict__ Qg, const unsigned short* __restrict__ Kg,
    const unsigned short* __restrict__ Vg,
    unsigned short* __restrict__ Op, float* __restrict__ Lp)
{
    // 128 KiB exactly: kbuf [2][64m][128k] swz (32 KB) | vbuf [3][2 half][256c][32m] swz (96 KB)
    __shared__ __align__(16) char smem[131072];
    unsigned short* kbuf = (unsigned short*)smem;             // 2 x 8192 el (16 KB each)
    unsigned short* vbuf = (unsigned short*)(smem + 32768);   // 3 x 16384 el (32 KB each)
    unsigned*       ex32 = (unsigned*)smem;                   // [4][8][8][64] u32 (64 KB), post-loop
    float*          lred = (float*)(smem + 65536);            // [8][32] (1 KB),  post-loop

    const int bid = blockIdx.x;              // 256 blocks
    const int mh  = bid & 1;                 // m-half
    const int set = (bid >> 1) & 3;
    const int att = set & 1, b = set >> 1;
    const int nt  = bid >> 3;                // 0..31
    const int n0g = nt * 128;
    const int mbase = mh * 2048;
    const int tid = threadIdx.x;
    const int lane = tid & 63, w = tid >> 6; // w 0..7
    const int nw = w & 3, mw = w >> 2;
    const int l31 = lane & 31, h = lane >> 5;

    const unsigned short* Qb = Qg + (size_t)b * HW * 128;
    const unsigned short* Kb = Kg + (size_t)(b * 2 + att) * HW * 128;
    const unsigned short* Vb = Vg + (size_t)(b * 2 + att) * (size_t)CDIM * HW;

    bf16x8 aQ[8];   // QK B-operand fragment; wave owns n-range n0g + nw*32
    {
        const int n = n0g + nw * 32 + l31;
#pragma unroll
        for (int kk = 0; kk < 8; ++kk)
            aQ[kk] = *(const bf16x8*)(Qb + (size_t)n * 128 + kk * 16 + h * 8);
    }

    f32x16 acc[8];
#pragma unroll
    for (int i = 0; i < 8; ++i)
#pragma unroll
        for (int r = 0; r < 16; ++r) acc[i][r] = 0.f;
    float lsum = 0.f;

    // per-lane global src pointers (r4 swizzle scheme, 64-m tile / 512 thr)
    // K: chunk L = t*512+tid (0..1023): ml=L>>4 (0..63), s=L&15, g=s^(ml&15)
    // V: chunk L = t*512+tid (0..2047): half=L>>10, c=(L&1023)>>2, s=L&3,
    //    g=s^((c>>2)&3); src m-offset = half*32 + g*8
    const unsigned short* ksrc[2];
    const unsigned short* vsrc[4];
#pragma unroll
    for (int t = 0; t < 2; ++t) {
        const int L = t * 512 + tid;
        const int ml = L >> 4, s = L & 15;
        ksrc[t] = Kb + (size_t)ml * 128 + (s ^ (ml & 15)) * 8;
    }
#pragma unroll
    for (int t = 0; t < 4; ++t) {
        const int L = t * 512 + tid;
        const int half = L >> 10, L1 = L & 1023;
        const int c = L1 >> 2, s = L1 & 3;
        vsrc[t] = Vb + (size_t)c * HW + half * 32 + (s ^ ((c >> 2) & 3)) * 8;
    }

    auto stage = [&](int mt) {
        const int kb = mt & 1;
        const int vb = mt % 3;
        const int m0 = mbase + mt * 64;
        char* kdl = (char*)kbuf + (size_t)kb * 16384 + (size_t)w * 1024;  // wave-uniform
        char* vdl = (char*)vbuf + (size_t)vb * 32768 + (size_t)w * 1024;
#pragma unroll
        for (int t = 0; t < 2; ++t)
            gl_lds16(ksrc[t] + (size_t)m0 * 128, kdl + (size_t)t * 8192);
#pragma unroll
        for (int t = 0; t < 4; ++t)
            gl_lds16(vsrc[t] + m0, vdl + (size_t)t * 8192);
    };

    auto QK = [&](int cur, f32x16& sa, f32x16& sb) {
        const unsigned short* kb_ = kbuf + cur * 8192 + mw * 4096;  // mw's 32-m half
#pragma unroll
        for (int r = 0; r < 16; ++r) { sa[r] = 0.f; sb[r] = 0.f; }
#pragma unroll
        for (int kk = 0; kk < 4; ++kk) {
            bf16x8 bK = *(const bf16x8*)&kb_[(l31 * 16 + ((kk * 2 + h) ^ (l31 & 15))) * 8];
            sa = __builtin_amdgcn_mfma_f32_32x32x16_bf16(bK, aQ[kk], sa, 0, 0, 0);
        }
#pragma unroll
        for (int kk = 4; kk < 8; ++kk) {
            bf16x8 bK = *(const bf16x8*)&kb_[(l31 * 16 + ((kk * 2 + h) ^ (l31 & 15))) * 8];
            sb = __builtin_amdgcn_mfma_f32_32x32x16_bf16(bK, aQ[kk], sb, 0, 0, 0);
        }
    };

    auto EXPP = [&](const f32x16& sa, const f32x16& sb, bf16x8* bP) {
        float p[16];
#pragma unroll
        for (int r = 0; r < 16; ++r) {
            p[r] = EXP2(sa[r] + sb[r]);     // Q pre-scaled by log2e
            lsum += p[r];
        }
#pragma unroll
        for (int k2 = 0; k2 < 2; ++k2) {
            const float* pp = p + k2 * 8;
            const unsigned a0 = pk2(pp[1], pp[0]);
            const unsigned a1 = pk2(pp[3], pp[2]);
            const unsigned b0 = pk2(pp[5], pp[4]);
            const unsigned b1 = pk2(pp[7], pp[6]);
            auto s0 = __builtin_amdgcn_permlane32_swap(a0, b0, false, false);
            auto s1 = __builtin_amdgcn_permlane32_swap(a1, b1, false, false);
            union { unsigned u[4]; bf16x8 v; } uu;
            uu.u[0] = s0[0];
            uu.u[1] = s1[0];
            uu.u[2] = s0[1];
            uu.u[3] = s1[1];
            bP[k2] = uu.v;
        }
    };

    auto PV = [&](int vprev, const bf16x8* bP) {
        const unsigned short* vb_ = vbuf + vprev * 16384 + mw * 8192;  // mw's half
#pragma unroll
        for (int cf = 0; cf < 8; ++cf) {
            const int c = cf * 32 + l31;
#pragma unroll
            for (int k2 = 0; k2 < 2; ++k2) {
                bf16x8 aV = *(const bf16x8*)&vb_[(c * 4 + ((k2 * 2 + h) ^ ((c >> 2) & 3))) * 8];
                acc[cf] = __builtin_amdgcn_mfma_f32_32x32x16_bf16(aV, bP[k2], acc[cf], 0, 0, 0);
            }
        }
    };

    // ---- pipelined main loop (r4 schedule): iter mt does QK(mt)+PV(mt-1) ----
    stage(0);
    __syncthreads();                        // K0,V0 ready
    stage(1);
    bf16x8 bP[2];
    {
        f32x16 sa, sb;
        QK(0, sa, sb);
        EXPP(sa, sb, bP);
    }
    int vprev = 0;                          // (mt-1)%3 for mt=1
#pragma unroll 1
    for (int mt = 1; mt < 32; ++mt) {
        __syncthreads();                    // drains stage(mt); prev PV reads done
        if (mt + 1 < 32) stage(mt + 1);
        f32x16 sa, sb;
        QK(mt & 1, sa, sb);
        PV(vprev, bP);
        EXPP(sa, sb, bP);
        vprev = (vprev == 2) ? 0 : vprev + 1;
    }
    PV(vprev, bP);                          // tail: PV(31) reads vbuf[1]

    // ---- on-chip reduction across mw pairs (LDS reused AFTER barrier) ----
    const float lw = lsum + __shfl_xor(lsum, 32, 64);
    __syncthreads();                        // ALL loop LDS reads retired
    if (h == 0) lred[w * 32 + l31] = lw;
    if (mw == 1) {
#pragma unroll
        for (int cf = 0; cf < 8; ++cf)
#pragma unroll
            for (int rp = 0; rp < 8; ++rp) {
                const unsigned v = ((unsigned)f2bf(acc[cf][rp * 2 + 1]) << 16)
                                 | f2bf(acc[cf][rp * 2]);
                ex32[(((w - 4) * 8 + cf) * 8 + rp) * 64 + lane] = v;
            }
    }
    __syncthreads();
    if (mw == 0) {
#pragma unroll
        for (int cf = 0; cf < 8; ++cf)
#pragma unroll
            for (int rp = 0; rp < 8; ++rp) {
                const unsigned v = ex32[((w * 8 + cf) * 8 + rp) * 64 + lane];
                acc[cf][rp * 2]     += bf2f((unsigned short)(v & 0xffffu));
                acc[cf][rp * 2 + 1] += bf2f((unsigned short)(v >> 16));
            }
        const float ltot = lred[w * 32 + l31] + lred[(w + 4) * 32 + l31];
        const int nn = n0g + nw * 32 + l31;
        if (h == 0) Lp[(size_t)(mh * 4 + set) * HW + nn] = ltot;

        const size_t obase = (size_t)(mh * 4 + set) * CDIM * HW;
#pragma unroll
        for (int cf = 0; cf < 8; ++cf) {
#pragma unroll
            for (int r = 0; r < 16; ++r) {
                const int c = cf * 32 + (r & 3) + 8 * (r >> 2) + 4 * h;
                Op[obase + (size_t)c * HW + nn] = f2bf(acc[cf][r]);
            }
        }
    }
}

// ---------------------------------------------------------------------------
// Kernel 3: combine partials: out = g*(O0+O1)/(l0+l1) + input.
// (r0-exact 2-partial version)
// ---------------------------------------------------------------------------
__global__ __launch_bounds__(256) void combine_kernel(
    const unsigned short* __restrict__ Op, const float* __restrict__ Lp,
    const float* __restrict__ in1, const float* __restrict__ in2,
    const float* __restrict__ gamma_p, float* __restrict__ out)
{
    const size_t i8 = ((size_t)blockIdx.x * 256 + threadIdx.x) * 8;
    const int oset = (int)(i8 >> 20);          // att*2 + b
    const int att = oset >> 1, b = oset & 1;
    const int pset = b * 2 + att;
    const size_t rem = i8 & 1048575u;          // c*HW + n
    const int n = (int)(i8 & 4095);

    const u16x8 o0 = *(const u16x8*)(Op + ((size_t)pset << 20) + rem);
    const u16x8 o1 = *(const u16x8*)(Op + ((size_t)pset << 20) + rem + ((size_t)4 << 20));
    const f32x4 la0 = *(const f32x4*)(Lp + (size_t)pset * HW + n);
    const f32x4 la1 = *(const f32x4*)(Lp + (size_t)pset * HW + n + 4);
    const f32x4 lb0 = *(const f32x4*)(Lp + (size_t)(4 + pset) * HW + n);
    const f32x4 lb1 = *(const f32x4*)(Lp + (size_t)(4 + pset) * HW + n + 4);
    const float* inb = (att ? in2 : in1) + (size_t)b * CDIM * HW + rem;
    const float g = *gamma_p;

    const f32x4 iv0 = *(const f32x4*)(inb);
    const f32x4 iv1 = *(const f32x4*)(inb + 4);
    f32x4 r0, r1;
#pragma unroll
    for (int j = 0; j < 4; ++j) {
        const float ov = bf2f((unsigned short)o0[j]) + bf2f((unsigned short)o1[j]);
        r0[j] = g * ov / (la0[j] + lb0[j]) + iv0[j];
    }
#pragma unroll
    for (int j = 0; j < 4; ++j) {
        const float ov = bf2f((unsigned short)o0[j + 4]) + bf2f((unsigned short)o1[j + 4]);
        r1[j] = g * ov / (la1[j] + lb1[j]) + iv1[j];
    }
    *(f32x4*)(out + i8) = r0;
    *(f32x4*)(out + i8 + 4) = r1;
}

extern "C" void kernel_launch(void* const* d_in, const int* in_sizes, int n_in,
                              void* d_out, int out_size, void* d_ws, size_t ws_size,
                              hipStream_t stream) {
    const float* in1 = (const float*)d_in[0];
    const float* in2 = (const float*)d_in[1];
    const float* Wq1 = (const float*)d_in[2];  const float* bq1 = (const float*)d_in[3];
    const float* Wk1 = (const float*)d_in[4];  const float* bk1 = (const float*)d_in[5];
    const float* Wv1 = (const float*)d_in[6];  const float* bv1 = (const float*)d_in[7];
    const float* Wq2 = (const float*)d_in[8];  const float* bq2 = (const float*)d_in[9];
    const float* Wk2 = (const float*)d_in[10]; const float* bk2 = (const float*)d_in[11];
    const float* Wv2 = (const float*)d_in[12]; const float* bv2 = (const float*)d_in[13];
    const float* gamma = (const float*)d_in[14];

    unsigned short* Qg = (unsigned short*)d_ws;                 // [2][4096 n][128 c]
    unsigned short* Kg = Qg + (size_t)2 * HW * 128;             // [4][4096 m][128 c]
    unsigned short* Vg = Kg + (size_t)4 * HW * 128;             // [4][256 c][4096 m]
    unsigned short* Op = Vg + (size_t)4 * CDIM * HW;            // [2 mh][4 set][256 c][4096 n] bf16
    float*          Lp = (float*)(Op + (size_t)8 * CDIM * HW);  // [2 mh][4 set][4096 n] f32
    unsigned short* Wpk = Op;   // aliases Op: live only wpack->proj, dead before attn

    wpack_kernel<<<224, 256, 0, stream>>>(Wq1, Wk1, Wv1, Wq2, Wk2, Wv2, Wpk);
    proj_kernel<<<512, 256, 0, stream>>>(in1, in2, bq1, bk1, bv1, bq2, bk2, bv2,
                                         Wpk, Qg, Kg, Vg);
    attn_kernel<<<256, 512, 0, stream>>>(Qg, Kg, Vg, Op, Lp);
    combine_kernel<<<2048, 256, 0, stream>>>(Op, Lp, in1, in2, gamma, (float*)d_out);
}